// Round 1
// baseline (143.482 us; speedup 1.0000x reference)
//
#include <hip/hip_runtime.h>
#include <math.h>

// Problem constants (from reference)
#define NCAMS 48      // B*NC = 8*6
#define NC_   6
#define A_    25200
#define C_    10
#define MAXGT 32
#define IOU_THR 0.5f
#define L_COORD 5.0f
#define L_NOOBJ 0.5f

// Decomposition
#define BLOCK  256
#define APT    8                  // anchors per thread
#define CHUNK  (BLOCK * APT)      // 2048 anchors per block
#define NCHUNK ((A_ + CHUNK - 1) / CHUNK)   // 13

__device__ __forceinline__ float softplus_f(float x) {
    // jax.nn.softplus(x) == logaddexp(x, 0) == max(x,0) + log1p(exp(-|x|))
    return fmaxf(x, 0.0f) + log1pf(expf(-fabsf(x)));
}

// Phase 1: per (cam, anchor-chunk) block -> 6 partial sums
//   [0]=pos_cnt [1]=neg_cnt [2]=box_se_sum [3]=softplus(-o) over pos
//   [4]=softplus(o) over neg [5]=ce_sum over pos
__global__ __launch_bounds__(BLOCK)
void yolo_phase1(const float* __restrict__ pred_boxes,   // (cams, A, 4)
                 const float* __restrict__ pred_labels,  // (cams, A, C)
                 const float* __restrict__ pred_obj,     // (cams, A, 1)
                 const float* __restrict__ gt_boxes,     // (TG, 4) cxcywh
                 const int*   __restrict__ gt_labels,    // (TG)
                 const int*   __restrict__ se,           // (B, NC)
                 int total_gt,
                 float* __restrict__ partials)           // (cams*NCHUNK, 8)
{
    const int cam   = blockIdx.y;
    const int chunk = blockIdx.x;
    const int tid   = threadIdx.x;

    __shared__ float4 s_corner[MAXGT];   // g1x, g1y, g2x, g2y
    __shared__ float4 s_orig[MAXGT];     // cx, cy, w, h (for box SE)
    __shared__ float  s_area[MAXGT];
    __shared__ int    s_lbl[MAXGT];
    __shared__ float  s_red[BLOCK / 64][6];

    // start/ngt for this cam (computed redundantly per thread; tiny, cached)
    const int b  = cam / NC_;
    const int nc = cam - b * NC_;
    int off = 0;
    for (int bb = 0; bb < b; ++bb) off += se[bb * NC_ + (NC_ - 1)];
    const int start = off + (nc ? se[b * NC_ + nc - 1] : 0);
    const int end   = off + se[b * NC_ + nc];
    int ngt = end - start;
    if (ngt < 0) ngt = 0;
    if (ngt > MAXGT) ngt = MAXGT;

    if (tid < ngt) {
        int gi = start + tid;
        gi = min(max(gi, 0), total_gt - 1);        // reference clips gidx
        float4 gb = ((const float4*)gt_boxes)[gi];
        float hw = gb.z * 0.5f, hh = gb.w * 0.5f;
        s_corner[tid] = make_float4(gb.x - hw, gb.y - hh, gb.x + hw, gb.y + hh);
        s_orig[tid]   = gb;
        s_area[tid]   = gb.z * gb.w;
        s_lbl[tid]    = gt_labels[gi];
    }
    __syncthreads();

    float pos_cnt = 0.f, neg_cnt = 0.f;
    float box_acc = 0.f, spp_acc = 0.f, spn_acc = 0.f, ce_acc = 0.f;

    const int base = chunk * CHUNK;
    const float4* pb4 = (const float4*)pred_boxes;

    #pragma unroll
    for (int j = 0; j < APT; ++j) {
        const int a = base + j * BLOCK + tid;
        if (a >= A_) continue;
        const long idx = (long)cam * A_ + a;

        const float4 p = pb4[idx];
        const float phw = p.z * 0.5f, phh = p.w * 0.5f;
        const float p1x = p.x - phw, p1y = p.y - phh;
        const float p2x = p.x + phw, p2y = p.y + phh;
        const float parea = p.z * p.w;

        // argmax IoU over valid GTs; strict '>' ascending k == jnp.argmax (first max)
        float best = -1.0f;
        int bk = 0;
        for (int k = 0; k < ngt; ++k) {
            const float4 g = s_corner[k];
            float wx = fminf(p2x, g.z) - fmaxf(p1x, g.x);
            float wy = fminf(p2y, g.w) - fmaxf(p1y, g.y);
            wx = fmaxf(wx, 0.0f);
            wy = fmaxf(wy, 0.0f);
            const float inter = wx * wy;
            const float iou = inter / (parea + s_area[k] - inter + 1e-6f);
            if (iou > best) { best = iou; bk = k; }
        }

        const float o = pred_obj[idx];
        if (best > IOU_THR) {            // ngt==0 -> best=-1 -> false (has_gt)
            pos_cnt += 1.0f;
            const float4 mb = s_orig[bk];
            const float dx = p.x - mb.x, dy = p.y - mb.y;
            const float dz = p.z - mb.z, dw = p.w - mb.w;
            box_acc += dx * dx + dy * dy + dz * dz + dw * dw;
            spp_acc += softplus_f(-o);
            // cross-entropy only for (rare) positives -> pred_labels mostly unread
            const float* lg = pred_labels + idx * C_;
            float m = lg[0];
            #pragma unroll
            for (int i = 1; i < C_; ++i) m = fmaxf(m, lg[i]);
            float sexp = 0.f;
            #pragma unroll
            for (int i = 0; i < C_; ++i) sexp += expf(lg[i] - m);
            const int lbl = s_lbl[bk];
            ce_acc += -(lg[lbl] - m - logf(sexp));
        } else {
            neg_cnt += 1.0f;
            spn_acc += softplus_f(o);
        }
    }

    // block reduction of 6 values
    float v[6] = {pos_cnt, neg_cnt, box_acc, spp_acc, spn_acc, ce_acc};
    #pragma unroll
    for (int i = 0; i < 6; ++i) {
        float x = v[i];
        for (int s = 32; s; s >>= 1) x += __shfl_down(x, s, 64);
        v[i] = x;
    }
    if ((tid & 63) == 0) {
        const int w = tid >> 6;
        #pragma unroll
        for (int i = 0; i < 6; ++i) s_red[w][i] = v[i];
    }
    __syncthreads();
    if (tid == 0) {
        float* outp = partials + (size_t)(cam * NCHUNK + chunk) * 8;
        #pragma unroll
        for (int i = 0; i < 6; ++i)
            outp[i] = s_red[0][i] + s_red[1][i] + s_red[2][i] + s_red[3][i];
    }
}

// Phase 2: one wave combines all partials with reference semantics.
__global__ void yolo_phase2(const float* __restrict__ partials,
                            float* __restrict__ out)
{
    const int t = threadIdx.x;   // 0..63
    float box_sum = 0.f, obj_sum = 0.f, noobj_sum = 0.f, cls_sum = 0.f;
    float np_ = 0.f, nn_ = 0.f;

    if (t < NCAMS) {
        float p = 0.f, n = 0.f, bx = 0.f, sp = 0.f, sn = 0.f, ce = 0.f;
        for (int h = 0; h < NCHUNK; ++h) {
            const float* q = partials + (size_t)(t * NCHUNK + h) * 8;
            p  += q[0]; n  += q[1]; bx += q[2];
            sp += q[3]; sn += q[4]; ce += q[5];
        }
        // per-cam contributions (reference: box is a sum, others safe_mean)
        box_sum   = L_COORD * bx;
        obj_sum   = (p > 0.f) ? sp / fmaxf(p, 1.0f) : 0.f;
        cls_sum   = (p > 0.f) ? ce / fmaxf(p, 1.0f) : 0.f;
        noobj_sum = L_NOOBJ * ((n > 0.f) ? sn / fmaxf(n, 1.0f) : 0.f);
        np_ = p; nn_ = n;
    }
    for (int s = 32; s; s >>= 1) {
        box_sum   += __shfl_down(box_sum, s, 64);
        obj_sum   += __shfl_down(obj_sum, s, 64);
        noobj_sum += __shfl_down(noobj_sum, s, 64);
        cls_sum   += __shfl_down(cls_sum, s, 64);
        np_       += __shfl_down(np_, s, 64);
        nn_       += __shfl_down(nn_, s, 64);
    }
    if (t == 0) {
        const float box_loss   = (np_ > 0.f) ? box_sum / fmaxf(np_, 1.0f) : 0.f;
        const float obj_loss   = (np_ > 0.f) ? obj_sum / fmaxf(np_, 1.0f) : 0.f;
        const float cls_loss   = (np_ > 0.f) ? cls_sum / fmaxf(np_, 1.0f) : 0.f;
        const float noobj_loss = (nn_ > 0.f) ? noobj_sum / fmaxf(nn_, 1.0f) : 0.f;
        const float total = box_loss + obj_loss + noobj_loss + cls_loss;
        out[0] = total;
        out[1] = box_loss;
        out[2] = obj_loss;
        out[3] = noobj_loss;
        out[4] = cls_loss;
    }
}

extern "C" void kernel_launch(void* const* d_in, const int* in_sizes, int n_in,
                              void* d_out, int out_size, void* d_ws, size_t ws_size,
                              hipStream_t stream) {
    const float* pred_boxes  = (const float*)d_in[0];
    const float* pred_labels = (const float*)d_in[1];
    const float* pred_obj    = (const float*)d_in[2];
    const float* gt_boxes    = (const float*)d_in[3];
    const int*   gt_labels   = (const int*)d_in[4];
    const int*   se          = (const int*)d_in[5];
    const int total_gt = in_sizes[3] / 4;

    float* partials = (float*)d_ws;   // NCAMS*NCHUNK*8 floats = 19.5 KB

    dim3 grid(NCHUNK, NCAMS);
    yolo_phase1<<<grid, BLOCK, 0, stream>>>(pred_boxes, pred_labels, pred_obj,
                                            gt_boxes, gt_labels, se,
                                            total_gt, partials);
    yolo_phase2<<<1, 64, 0, stream>>>(partials, (float*)d_out);
}

// Round 2
// 124.015 us; speedup vs baseline: 1.1570x; 1.1570x over previous
//
#include <hip/hip_runtime.h>
#include <math.h>

// Problem constants (from reference)
#define NCAMS 48      // B*NC = 8*6
#define NC_   6
#define A_    25200
#define C_    10
#define MAXGT 32
#define IOU_THR 0.5f
#define L_COORD 5.0f
#define L_NOOBJ 0.5f

// Decomposition: 2 anchors per thread -> 2400 blocks (vs 624 last round).
// block=256: 4 waves/block, 8 blocks/CU resident (32-wave cap) -> ~full occupancy.
#define BLOCK  256
#define CHUNK  (BLOCK * 2)        // 512 anchors per block
#define NCHUNK ((A_ + CHUNK - 1) / CHUNK)   // 50

__device__ __forceinline__ float softplus_f(float x) {
    return fmaxf(x, 0.0f) + log1pf(expf(-fabsf(x)));
}

// Phase 1: per (cam, anchor-chunk) block -> 6 partial sums
__global__ __launch_bounds__(BLOCK)
void yolo_phase1(const float* __restrict__ pred_boxes,   // (cams, A, 4)
                 const float* __restrict__ pred_labels,  // (cams, A, C)
                 const float* __restrict__ pred_obj,     // (cams, A, 1)
                 const float* __restrict__ gt_boxes,     // (TG, 4) cxcywh
                 const int*   __restrict__ gt_labels,    // (TG)
                 const int*   __restrict__ se,           // (B, NC)
                 int total_gt,
                 float* __restrict__ partials)           // (cams*NCHUNK, 8)
{
    const int cam   = blockIdx.y;
    const int chunk = blockIdx.x;
    const int tid   = threadIdx.x;

    __shared__ float4 s_corner[MAXGT];   // g1x, g1y, g2x, g2y
    __shared__ float4 s_orig[MAXGT];     // cx, cy, w, h (for box SE)
    __shared__ float  s_area[MAXGT];
    __shared__ int    s_lbl[MAXGT];
    __shared__ float  s_red[BLOCK / 64][6];

    const int b  = cam / NC_;
    const int nc = cam - b * NC_;
    int off = 0;
    for (int bb = 0; bb < b; ++bb) off += se[bb * NC_ + (NC_ - 1)];
    const int start = off + (nc ? se[b * NC_ + nc - 1] : 0);
    const int end   = off + se[b * NC_ + nc];
    int ngt = end - start;
    if (ngt < 0) ngt = 0;
    if (ngt > MAXGT) ngt = MAXGT;

    if (tid < ngt) {
        int gi = start + tid;
        gi = min(max(gi, 0), total_gt - 1);   // reference clips gidx
        float4 gb = ((const float4*)gt_boxes)[gi];
        float hw = gb.z * 0.5f, hh = gb.w * 0.5f;
        s_corner[tid] = make_float4(gb.x - hw, gb.y - hh, gb.x + hw, gb.y + hh);
        s_orig[tid]   = gb;
        s_area[tid]   = gb.z * gb.w;
        s_lbl[tid]    = gt_labels[gi];
    }
    __syncthreads();

    const int base = chunk * CHUNK;
    const int a0 = base + tid;
    const int a1 = base + BLOCK + tid;
    const bool valid0 = (a0 < A_);
    const bool valid1 = (a1 < A_);
    const int a0c = valid0 ? a0 : (A_ - 1);
    const int a1c = valid1 ? a1 : (A_ - 1);
    const long long idx0 = (long long)cam * A_ + a0c;
    const long long idx1 = (long long)cam * A_ + a1c;

    const float4* pb4 = (const float4*)pred_boxes;
    const float4 p0 = pb4[idx0];
    const float4 p1 = pb4[idx1];
    const float o0 = pred_obj[idx0];     // load early, used after k-loop
    const float o1 = pred_obj[idx1];

    const float p1x0 = p0.x - p0.z * 0.5f, p1y0 = p0.y - p0.w * 0.5f;
    const float p2x0 = p0.x + p0.z * 0.5f, p2y0 = p0.y + p0.w * 0.5f;
    const float pa0  = p0.z * p0.w + 1e-6f;
    const float p1x1 = p1.x - p1.z * 0.5f, p1y1 = p1.y - p1.w * 0.5f;
    const float p2x1 = p1.x + p1.z * 0.5f, p2y1 = p1.y + p1.w * 0.5f;
    const float pa1  = p1.z * p1.w + 1e-6f;

    float best0 = -1.0f, best1 = -1.0f;
    int bk0 = 0, bk1 = 0;

    // argmax IoU; strict '>' ascending k == jnp.argmax (first max).
    // fast rcp (~1 ulp) instead of precise div: argmax flip risk negligible.
    auto iou_step = [&](int k) {
        const float4 g = s_corner[k];
        const float ga = s_area[k];
        float wx0 = fmaxf(fminf(p2x0, g.z) - fmaxf(p1x0, g.x), 0.0f);
        float wy0 = fmaxf(fminf(p2y0, g.w) - fmaxf(p1y0, g.y), 0.0f);
        float wx1 = fmaxf(fminf(p2x1, g.z) - fmaxf(p1x1, g.x), 0.0f);
        float wy1 = fmaxf(fminf(p2y1, g.w) - fmaxf(p1y1, g.y), 0.0f);
        const float inter0 = wx0 * wy0;
        const float inter1 = wx1 * wy1;
        const float iou0 = inter0 * __builtin_amdgcn_rcpf(pa0 + (ga - inter0));
        const float iou1 = inter1 * __builtin_amdgcn_rcpf(pa1 + (ga - inter1));
        if (iou0 > best0) { best0 = iou0; bk0 = k; }
        if (iou1 > best1) { best1 = iou1; bk1 = k; }
    };

    if (ngt == 20) {                 // hot path in this dataset: full unroll
        #pragma unroll
        for (int k = 0; k < 20; ++k) iou_step(k);
    } else {
        for (int k = 0; k < ngt; ++k) iou_step(k);
    }

    float pos_cnt = 0.f, neg_cnt = 0.f;
    float box_acc = 0.f, spp_acc = 0.f, spn_acc = 0.f, ce_acc = 0.f;

    auto accumulate = [&](bool valid, float best, int bk, const float4& p,
                          float o, long long idx) {
        if (!valid) return;
        if (best > IOU_THR) {        // ngt==0 -> best=-1 -> negative (has_gt)
            pos_cnt += 1.0f;
            const float4 mb = s_orig[bk];
            const float dx = p.x - mb.x, dy = p.y - mb.y;
            const float dz = p.z - mb.z, dw = p.w - mb.w;
            box_acc += dx * dx + dy * dy + dz * dz + dw * dw;
            spp_acc += softplus_f(-o);
            const float* lg = pred_labels + idx * C_;   // rare: labels mostly unread
            float m = lg[0];
            #pragma unroll
            for (int i = 1; i < C_; ++i) m = fmaxf(m, lg[i]);
            float sexp = 0.f;
            #pragma unroll
            for (int i = 0; i < C_; ++i) sexp += expf(lg[i] - m);
            const int lbl = s_lbl[bk];
            ce_acc += -(lg[lbl] - m - logf(sexp));
        } else {
            neg_cnt += 1.0f;
            spn_acc += softplus_f(o);
        }
    };
    accumulate(valid0, best0, bk0, p0, o0, idx0);
    accumulate(valid1, best1, bk1, p1, o1, idx1);

    // block reduction of 6 values
    float v[6] = {pos_cnt, neg_cnt, box_acc, spp_acc, spn_acc, ce_acc};
    #pragma unroll
    for (int i = 0; i < 6; ++i) {
        float x = v[i];
        for (int s = 32; s; s >>= 1) x += __shfl_down(x, s, 64);
        v[i] = x;
    }
    if ((tid & 63) == 0) {
        const int w = tid >> 6;
        #pragma unroll
        for (int i = 0; i < 6; ++i) s_red[w][i] = v[i];
    }
    __syncthreads();
    if (tid == 0) {
        float* outp = partials + (size_t)(cam * NCHUNK + chunk) * 8;
        #pragma unroll
        for (int i = 0; i < 6; ++i)
            outp[i] = s_red[0][i] + s_red[1][i] + s_red[2][i] + s_red[3][i];
    }
}

// Phase 2: one wave combines all partials with reference semantics.
__global__ void yolo_phase2(const float* __restrict__ partials,
                            float* __restrict__ out)
{
    const int t = threadIdx.x;   // 0..63
    float box_sum = 0.f, obj_sum = 0.f, noobj_sum = 0.f, cls_sum = 0.f;
    float np_ = 0.f, nn_ = 0.f;

    if (t < NCAMS) {
        float p = 0.f, n = 0.f, bx = 0.f, sp = 0.f, sn = 0.f, ce = 0.f;
        for (int h = 0; h < NCHUNK; ++h) {
            const float* q = partials + (size_t)(t * NCHUNK + h) * 8;
            p  += q[0]; n  += q[1]; bx += q[2];
            sp += q[3]; sn += q[4]; ce += q[5];
        }
        box_sum   = L_COORD * bx;
        obj_sum   = (p > 0.f) ? sp / fmaxf(p, 1.0f) : 0.f;
        cls_sum   = (p > 0.f) ? ce / fmaxf(p, 1.0f) : 0.f;
        noobj_sum = L_NOOBJ * ((n > 0.f) ? sn / fmaxf(n, 1.0f) : 0.f);
        np_ = p; nn_ = n;
    }
    for (int s = 32; s; s >>= 1) {
        box_sum   += __shfl_down(box_sum, s, 64);
        obj_sum   += __shfl_down(obj_sum, s, 64);
        noobj_sum += __shfl_down(noobj_sum, s, 64);
        cls_sum   += __shfl_down(cls_sum, s, 64);
        np_       += __shfl_down(np_, s, 64);
        nn_       += __shfl_down(nn_, s, 64);
    }
    if (t == 0) {
        const float box_loss   = (np_ > 0.f) ? box_sum / fmaxf(np_, 1.0f) : 0.f;
        const float obj_loss   = (np_ > 0.f) ? obj_sum / fmaxf(np_, 1.0f) : 0.f;
        const float cls_loss   = (np_ > 0.f) ? cls_sum / fmaxf(np_, 1.0f) : 0.f;
        const float noobj_loss = (nn_ > 0.f) ? noobj_sum / fmaxf(nn_, 1.0f) : 0.f;
        const float total = box_loss + obj_loss + noobj_loss + cls_loss;
        out[0] = total;
        out[1] = box_loss;
        out[2] = obj_loss;
        out[3] = noobj_loss;
        out[4] = cls_loss;
    }
}

extern "C" void kernel_launch(void* const* d_in, const int* in_sizes, int n_in,
                              void* d_out, int out_size, void* d_ws, size_t ws_size,
                              hipStream_t stream) {
    const float* pred_boxes  = (const float*)d_in[0];
    const float* pred_labels = (const float*)d_in[1];
    const float* pred_obj    = (const float*)d_in[2];
    const float* gt_boxes    = (const float*)d_in[3];
    const int*   gt_labels   = (const int*)d_in[4];
    const int*   se          = (const int*)d_in[5];
    const int total_gt = in_sizes[3] / 4;

    float* partials = (float*)d_ws;   // NCAMS*NCHUNK*8 floats = 75 KB

    dim3 grid(NCHUNK, NCAMS);
    yolo_phase1<<<grid, BLOCK, 0, stream>>>(pred_boxes, pred_labels, pred_obj,
                                            gt_boxes, gt_labels, se,
                                            total_gt, partials);
    yolo_phase2<<<1, 64, 0, stream>>>(partials, (float*)d_out);
}